// Round 2
// 291.793 us; speedup vs baseline: 1.0626x; 1.0626x over previous
//
#include <hip/hip_runtime.h>
#include <hip/hip_fp16.h>
#include <math.h>

#define LUT_D 33
#define LUT_D3 35937   // 33^3
#define NEG 0.2f
#define BATCH 4
#define HW_IMG 1048576 // 1024*1024

// ---------------- resize 1024 -> 256 (half-pixel bilinear, scale 4 => frac=0.5) -------------
__global__ void k_resize(const float* __restrict__ lq, float* __restrict__ out) {
    int gid = blockIdx.x * 256 + threadIdx.x;     // over 4*3*256*256 = 786432
    if (gid >= BATCH * 3 * 256 * 256) return;
    int x  = gid & 255;
    int y  = (gid >> 8) & 255;
    int pc = gid >> 16;                            // b*3 + c
    const float* in = lq + (size_t)pc * HW_IMG;
    const float* p0 = in + (4 * y + 1) * 1024 + (4 * x + 1);
    out[gid] = 0.25f * (p0[0] + p0[1] + p0[1024] + p0[1025]);
}

// ---------------- tiled conv3x3 s2 p1 (+LeakyReLU if NSPLIT==1), fused input-norm -----------
// block = (b, ty, tx, icc, ocg); 256 threads = 64 px * 4 oc-lanes (4 oc each).
// LDS tile rows: [pad pad pad | halo | 16 aligned floats] stride 20 -> float4 staging.
// NSPLIT>1: block computes partial over its ic-slice, writes raw partials (k_combine finishes).
// NORM_IN: input normalized on the fly via precomputed (sc,sh) pairs in nrm_in.
// STATS_OUT (NSPLIT==1 only): per-(oc,tile) wave partial sums of activated outputs.
template<int IC, int OC, int OH, int OW, int NSPLIT, bool NORM_IN, bool STATS_OUT>
__global__ void __launch_bounds__(256) k_conv_t(
    const float* __restrict__ in, const float* __restrict__ nrm_in,
    const float* __restrict__ w, const float* __restrict__ bias,
    float* __restrict__ out, float* __restrict__ part) {
    constexpr int IH = OH * 2, IW = OW * 2;
    constexpr int ICB = IC / NSPLIT;              // <= 32
    constexpr int TROW = 20, TSZ = 17 * TROW;     // 340 floats per ic tile
    constexpr int WQ = ICB * 9 / 4;               // float4s per oc slice
    constexpr int NTX = OW / 8, NTY = OH / 8, NOCG = OC / 16;
    constexpr int NT = NTX * NTY;
    constexpr int PX = OH * OW;

    __shared__ float sIn[ICB * TSZ];
    __shared__ float swl[16 * ICB * 9];
    __shared__ float sNm[NORM_IN ? ICB * 2 : 1];

    int id = blockIdx.x;
    int ocg   = id % NOCG;   id /= NOCG;
    int icc_i = id % NSPLIT; id /= NSPLIT;
    int tx    = id % NTX;    id /= NTX;
    int ty    = id % NTY;    id /= NTY;
    int b     = id;
    int icc   = icc_i * ICB;

    int t    = threadIdx.x;
    int lane = t >> 6;          // 0..3
    int px   = t & 63;
    int py   = px >> 3, pxx = px & 7;
    int oc0  = ocg * 16 + lane * 4;

    // ---- stage weights (vectorized) + norm pairs ----
    if (IC == ICB) {
        const float4* wsrc = (const float4*)(w + (size_t)ocg * 16 * IC * 9);
        for (int i = t; i < 16 * IC * 9 / 4; i += 256) ((float4*)swl)[i] = wsrc[i];
    } else {
        for (int i = t; i < 16 * WQ; i += 256) {
            int ol = i / WQ, qi = i % WQ;
            ((float4*)swl)[ol * WQ + qi] =
                *(const float4*)(w + ((size_t)(ocg * 16 + ol) * IC + icc) * 9 + qi * 4);
        }
    }
    if (NORM_IN) {
        for (int i = t; i < ICB * 2; i += 256) sNm[i] = nrm_in[(b * IC + icc) * 2 + i];
    }
    __syncthreads();

    // ---- stage input tile: 4 float4 + 1 halo scalar per (ic,row) ----
    int iy0 = ty * 16 - 1;
    int xbase = tx * 16;
    const float* inb = in + (size_t)(b * IC + icc) * (IH * IW);
    for (int q = t; q < ICB * 17 * 4; q += 256) {
        int ic_l = q / 68;
        int r    = q % 68;
        int row  = r >> 2, quad = r & 3;
        int iy = iy0 + row;
        float4 v = {0.f, 0.f, 0.f, 0.f};
        if (iy >= 0 && iy < IH) {
            v = *(const float4*)(inb + (size_t)ic_l * (IH * IW) + (size_t)iy * IW + xbase + quad * 4);
            if (NORM_IN) {
                float sc = sNm[ic_l * 2], sh = sNm[ic_l * 2 + 1];
                v.x = v.x * sc + sh; v.y = v.y * sc + sh;
                v.z = v.z * sc + sh; v.w = v.w * sc + sh;
            }
        }
        *(float4*)(sIn + ic_l * TSZ + row * TROW + 4 + quad * 4) = v;
    }
    for (int h = t; h < ICB * 17; h += 256) {
        int ic_l = h / 17, row = h % 17;
        int iy = iy0 + row, ix = xbase - 1;
        float v = 0.f;
        if (iy >= 0 && iy < IH && ix >= 0) {
            v = inb[(size_t)ic_l * (IH * IW) + (size_t)iy * IW + ix];
            if (NORM_IN) v = v * sNm[ic_l * 2] + sNm[ic_l * 2 + 1];
        }
        sIn[ic_l * TSZ + row * TROW + 3] = v;
    }
    __syncthreads();

    // ---- compute ----
    float acc[4];
    #pragma unroll
    for (int j = 0; j < 4; j++) acc[j] = (NSPLIT == 1) ? bias[oc0 + j] : 0.f;

    for (int i2 = 0; i2 < ICB; i2++) {
        const float* tp = sIn + i2 * TSZ + py * 2 * TROW + pxx * 2 + 3;
        float x0 = tp[0],        x1 = tp[1],        x2 = tp[2];
        float x3 = tp[TROW],     x4 = tp[TROW + 1], x5 = tp[TROW + 2];
        float x6 = tp[2 * TROW], x7 = tp[2 * TROW + 1], x8 = tp[2 * TROW + 2];
        #pragma unroll
        for (int j = 0; j < 4; j++) {
            const float* wp = swl + ((lane * 4 + j) * ICB + i2) * 9;
            acc[j] = fmaf(x0, wp[0], acc[j]);
            acc[j] = fmaf(x1, wp[1], acc[j]);
            acc[j] = fmaf(x2, wp[2], acc[j]);
            acc[j] = fmaf(x3, wp[3], acc[j]);
            acc[j] = fmaf(x4, wp[4], acc[j]);
            acc[j] = fmaf(x5, wp[5], acc[j]);
            acc[j] = fmaf(x6, wp[6], acc[j]);
            acc[j] = fmaf(x7, wp[7], acc[j]);
            acc[j] = fmaf(x8, wp[8], acc[j]);
        }
    }

    int oy = ty * 8 + py, ox = tx * 8 + pxx;
    if (NSPLIT == 1) {
        int tile = ty * NTX + tx;
        #pragma unroll
        for (int j = 0; j < 4; j++) {
            float a = acc[j];
            a = a >= 0.f ? a : NEG * a;
            out[((size_t)(b * OC + oc0 + j) * OH + oy) * OW + ox] = a;
            if (STATS_OUT) {
                float s1 = a, s2 = a * a;
                for (int off = 32; off > 0; off >>= 1) {
                    s1 += __shfl_down(s1, off, 64);
                    s2 += __shfl_down(s2, off, 64);
                }
                if (px == 0) {
                    size_t pi = ((size_t)(b * OC + oc0 + j) * NT + tile) * 2;
                    part[pi] = s1; part[pi + 1] = s2;
                }
            }
        }
    } else {
        #pragma unroll
        for (int j = 0; j < 4; j++) {
            part[(size_t)icc_i * (BATCH * OC * PX) +
                 (size_t)(b * OC + oc0 + j) * PX + oy * OW + ox] = acc[j];
        }
    }
}

// ---------------- combine ic-split partials: + bias, LeakyReLU, optional stats -------------
template<int NSPLIT, int OC, int PX, bool STATS>
__global__ void k_combine(const float* __restrict__ ps, const float* __restrict__ bias,
                          float* __restrict__ out, float* __restrict__ spart) {
    constexpr int TOT = BATCH * OC * PX;
    int e = blockIdx.x * 256 + threadIdx.x;
    if (e >= TOT) return;
    float s = 0.f;
    #pragma unroll
    for (int k = 0; k < NSPLIT; k++) s += ps[(size_t)k * TOT + e];
    int oc = (e / PX) % OC;
    s += bias[oc];
    s = s >= 0.f ? s : NEG * s;
    out[e] = s;
    if (STATS) {
        float s1 = s, s2 = s * s;
        for (int off = 32; off > 0; off >>= 1) {
            s1 += __shfl_down(s1, off, 64);
            s2 += __shfl_down(s2, off, 64);
        }
        if ((threadIdx.x & 63) == 0) {
            int widx = e >> 6;
            spart[widx * 2] = s1; spart[widx * 2 + 1] = s2;
        }
    }
}

// ---------------- reduce partial (s1,s2) -> per-(b,c) norm pair (scale, shift) -------------
template<int NT>
__global__ void k_norm(const float* __restrict__ part, const float* __restrict__ g,
                       const float* __restrict__ be, float invN, int C,
                       float* __restrict__ nrm) {
    int bc = blockIdx.x;
    int t  = threadIdx.x;  // 64
    float s1 = 0.f, s2 = 0.f;
    for (int i = t; i < NT; i += 64) {
        s1 += part[((size_t)bc * NT + i) * 2];
        s2 += part[((size_t)bc * NT + i) * 2 + 1];
    }
    #pragma unroll
    for (int off = 32; off > 0; off >>= 1) {
        s1 += __shfl_down(s1, off, 64);
        s2 += __shfl_down(s2, off, 64);
    }
    if (t == 0) {
        int c = bc % C;
        float m   = s1 * invN;
        float var = s2 * invN - m * m;
        float sc  = g[c] * rsqrtf(var + 1e-5f);
        nrm[bc * 2]     = sc;
        nrm[bc * 2 + 1] = be[c] - m * sc;
    }
}

// ---------------- AdaptiveAvgPool2d(2) on [4,128,8,8] -> codes [4,512] ---------------------
__global__ void k_pool(const float* __restrict__ f5, float* __restrict__ codes) {
    int c = blockIdx.x * 256 + threadIdx.x;   // 2048
    if (c >= 2048) return;
    int b = c >> 9;
    int rest = c & 511;
    int oc = rest >> 2, q = rest & 3;
    int py = (q >> 1) * 4, px = (q & 1) * 4;
    const float* p = f5 + ((size_t)(b * 128 + oc)) * 64;
    float s = 0.f;
    #pragma unroll
    for (int dy = 0; dy < 4; dy++)
        #pragma unroll
        for (int dx = 0; dx < 4; dx++)
            s += p[(py + dy) * 8 + px + dx];
    codes[c] = s * (1.f / 16.f);
}

// ---------------- heads: weights = codes@lw.T+lb ; vertices = pad(cumsum(softmax(...))) ----
// Also builds a 256-bin inverse-CDF acceleration table per (b,ch):
//   stab[u] = #{m in [0,33): v[m] <= u/256}   (uint8)
// x*256 and u*(1/256) are exact in fp32 (pow-2 scaling), so the table start index is always
// a valid lower bound for searchsorted(side='right'); k_transform fixes up with <=1 step typ.
__global__ void k_head(const float* __restrict__ codes, const float* __restrict__ lw,
                       const float* __restrict__ lb, const float* __restrict__ aw,
                       const float* __restrict__ ab, float* __restrict__ wt,
                       float* __restrict__ vert, float* __restrict__ stab,
                       float* __restrict__ out_w, float* __restrict__ out_v) {
    int blk = blockIdx.x;
    int t = threadIdx.x;  // 64 threads
    if (blk == 12) {
        if (t < 12) {
            int b = t / 3, j = t % 3;
            const float* c = codes + b * 512;
            const float* l = lw + j * 512;
            float s = lb[j];
            for (int k = 0; k < 512; k++) s += c[k] * l[k];
            wt[t] = s;
            out_w[t] = s;
        }
        return;
    }
    int b = blk / 3, ch = blk % 3;
    __shared__ float y[32];
    __shared__ float vsh[33];
    if (t < 32) {
        const float* c = codes + b * 512;
        const float* a = aw + (size_t)(ch * 32 + t) * 512;
        float s = ab[ch * 32 + t];
        for (int k = 0; k < 512; k++) s += c[k] * a[k];
        y[t] = s;
    }
    __syncthreads();
    if (t == 0) {
        float mx = y[0];
        for (int m = 1; m < 32; m++) mx = fmaxf(mx, y[m]);
        float e[32];
        float sum = 0.f;
        for (int m = 0; m < 32; m++) { e[m] = expf(y[m] - mx); sum += e[m]; }
        float inv = 1.f / sum;
        float cum = 0.f;
        float* vb = vert + (b * 3 + ch) * 33;
        float* ob = out_v + (b * 3 + ch) * 33;
        vb[0] = 0.f; ob[0] = 0.f; vsh[0] = 0.f;
        for (int m = 0; m < 32; m++) {
            cum += e[m] * inv;
            vb[m + 1] = cum; ob[m + 1] = cum; vsh[m + 1] = cum;
        }
    }
    __syncthreads();
    unsigned char* sb = (unsigned char*)stab + (b * 3 + ch) * 256;
    for (int u = t; u < 256; u += 64) {
        float lo = (float)u * (1.f / 256.f);   // exact
        int cnt = 0;
        #pragma unroll
        for (int m = 0; m < 33; m++) cnt += (vsh[m] <= lo) ? 1 : 0;
        sb[u] = (unsigned char)cnt;
    }
}

// ---------------- LUT generation: fp16 blue-pair entries ------------------------------------
// entry[(i*33+j)*33+k] = halves [r(k),g(k),b(k),r(k+1),g(k+1),b(k+1),0,0]  (16 B)
__global__ void k_lutgen(const float* __restrict__ bw, const float* __restrict__ wt,
                         float4* __restrict__ lutp) {
    int gid = blockIdx.x * 256 + threadIdx.x;     // over 4*35937
    if (gid >= BATCH * LUT_D3) return;
    int b = gid / LUT_D3;
    int cell = gid - b * LUT_D3;
    int k = cell % LUT_D;
    int cn = (k < LUT_D - 1) ? cell + 1 : cell;
    float w0 = wt[b * 3], w1 = wt[b * 3 + 1], w2 = wt[b * 3 + 2];
    const float* r0p = bw + (size_t)(0 * LUT_D3 + cell) * 3;
    const float* g0p = bw + (size_t)(1 * LUT_D3 + cell) * 3;
    const float* b0p = bw + (size_t)(2 * LUT_D3 + cell) * 3;
    const float* r1p = bw + (size_t)(0 * LUT_D3 + cn) * 3;
    const float* g1p = bw + (size_t)(1 * LUT_D3 + cn) * 3;
    const float* b1p = bw + (size_t)(2 * LUT_D3 + cn) * 3;
    union { float4 f4; __half h[8]; } u;
    u.h[0] = __float2half_rn(r0p[0] * w0 + r0p[1] * w1 + r0p[2] * w2);
    u.h[1] = __float2half_rn(g0p[0] * w0 + g0p[1] * w1 + g0p[2] * w2);
    u.h[2] = __float2half_rn(b0p[0] * w0 + b0p[1] * w1 + b0p[2] * w2);
    u.h[3] = __float2half_rn(r1p[0] * w0 + r1p[1] * w1 + r1p[2] * w2);
    u.h[4] = __float2half_rn(g1p[0] * w0 + g1p[1] * w1 + g1p[2] * w2);
    u.h[5] = __float2half_rn(b1p[0] * w0 + b1p[1] * w1 + b1p[2] * w2);
    u.h[6] = __float2half_rn(0.f);
    u.h[7] = __float2half_rn(0.f);
    lutp[gid] = u.f4;
}

// ---------------- cell-gather table: one 48B record per (i0,j0,k0) cell, 64B stride --------
// record halves [0..23] = corners {(i0,j0),(i0,j0+1),(i0+1,j0),(i0+1,j0+1)}, each
// (r(k0),g(k0),b(k0),r(k0+1),g(k0+1),b(k0+1)). 64B stride => record always inside ONE
// 128B cache line; k_transform fetches 1 line/pixel instead of 4 scattered lines.
__global__ void k_cellgen(const float4* __restrict__ lutp, float4* __restrict__ cells) {
    int gid = blockIdx.x * 256 + threadIdx.x;     // 4*32768 = 131072
    if (gid >= BATCH * 32768) return;
    int b = gid >> 15;
    int cell = gid & 32767;
    int k0 = cell & 31, j0 = (cell >> 5) & 31, i0 = cell >> 10;
    const float4* L = lutp + (size_t)b * LUT_D3;
    int base = (i0 * LUT_D + j0) * LUT_D + k0;
    float4 e00 = L[base];
    float4 e01 = L[base + LUT_D];
    float4 e10 = L[base + LUT_D * LUT_D];
    float4 e11 = L[base + LUT_D * LUT_D + LUT_D];
    float4 o0, o1, o2;
    o0.x = e00.x; o0.y = e00.y; o0.z = e00.z;   // c00 words 0..2
    o0.w = e01.x; o1.x = e01.y; o1.y = e01.z;   // c01 words 0..2
    o1.z = e10.x; o1.w = e10.y; o2.x = e10.z;   // c10 words 0..2
    o2.y = e11.x; o2.z = e11.y; o2.w = e11.z;   // c11 words 0..2
    float4* dst = cells + (size_t)gid * 4;      // 4th slot never written/read
    dst[0] = o0; dst[1] = o1; dst[2] = o2;
}

// ---------------- per-pixel accel search + trilinear LUT sample ----------------------------
// tab[u] = count of vertices <= u/256 (valid lower bound since u = floor(x*256) => u/256 <= x
// exactly). Fix-up loop advances while v[idx] <= x  == searchsorted(side='right').
__device__ __forceinline__ void searchA(const float* __restrict__ v,
                                        const unsigned char* __restrict__ tab,
                                        float x, int& i0, float& f) {
    int u = (int)(x * 256.f);
    u = u < 0 ? 0 : (u > 255 ? 255 : u);
    int idx = tab[u];
    while (idx < LUT_D && v[idx] <= x) idx++;
    idx = idx < 1 ? 1 : (idx > LUT_D - 1 ? LUT_D - 1 : idx);
    float vl = v[idx - 1], vh = v[idx];
    float fr = (x - vl) / (vh - vl + 1e-8f);
    float coord = (float)(idx - 1) + fr;
    coord = fminf(fmaxf(coord, 0.f), (float)(LUT_D - 1));
    i0 = (int)coord;
    if (i0 > LUT_D - 2) i0 = LUT_D - 2;
    f = coord - (float)i0;
}

// decode one corner (3 packed fp16 words = r0,g0,b0,r1,g1,b1), lerp along blue
__device__ __forceinline__ void decode_lerp3(float wa, float wb, float wc, float fb,
                                             float& rv, float& gv, float& bv) {
    union { float f; __half2 h; } u0, u1, u2;
    u0.f = wa; u1.f = wb; u2.f = wc;
    float2 a = __half22float2(u0.h);   // r0, g0
    float2 b = __half22float2(u1.h);   // b0, r1
    float2 c = __half22float2(u2.h);   // g1, b1
    rv = fmaf(fb, b.y - a.x, a.x);
    gv = fmaf(fb, c.x - a.y, a.y);
    bv = fmaf(fb, c.y - b.x, b.x);
}

__global__ void __launch_bounds__(256) k_transform(const float* __restrict__ lq,
                                                   const float4* __restrict__ cells,
                                                   const float* __restrict__ vert,
                                                   const unsigned char* __restrict__ stab,
                                                   float* __restrict__ out) {
    int bimg = blockIdx.x >> 10;                  // 1024 blocks per image
    int blk  = blockIdx.x & 1023;
    __shared__ float sv[3 * LUT_D];
    __shared__ unsigned char st[768];
    if (threadIdx.x < 3 * LUT_D) sv[threadIdx.x] = vert[bimg * 3 * LUT_D + threadIdx.x];
    if (threadIdx.x < 192)
        ((unsigned int*)st)[threadIdx.x] = ((const unsigned int*)stab)[bimg * 192 + threadIdx.x];
    __syncthreads();
    int p0 = blk * 1024 + threadIdx.x * 4;        // 4 px per thread
    const float* lr = lq + (size_t)bimg * 3 * HW_IMG + p0;
    float4 r4 = *(const float4*)(lr);
    float4 g4 = *(const float4*)(lr + HW_IMG);
    float4 b4 = *(const float4*)(lr + 2 * HW_IMG);
    float rr[4] = {r4.x, r4.y, r4.z, r4.w};
    float gg[4] = {g4.x, g4.y, g4.z, g4.w};
    float bb[4] = {b4.x, b4.y, b4.z, b4.w};

    // phase 1: all searches (12 independent short chains)
    int cidx[4];
    float fra[4], fga[4], fba[4];
    #pragma unroll
    for (int i = 0; i < 4; i++) {
        int i0, j0, k0;
        searchA(sv,      st,       rr[i], i0, fra[i]);
        searchA(sv + 33, st + 256, gg[i], j0, fga[i]);
        searchA(sv + 66, st + 512, bb[i], k0, fba[i]);
        cidx[i] = ((i0 * 32 + j0) << 5) + k0;
    }
    // phase 2: issue all cell loads (4 independent lines -> max MLP)
    float4 c0[4], c1[4], c2[4];
    #pragma unroll
    for (int i = 0; i < 4; i++) {
        const float4* p = cells + (((size_t)(bimg << 15) + cidx[i]) << 2);
        c0[i] = p[0]; c1[i] = p[1]; c2[i] = p[2];
    }
    // phase 3: decode + bilinear blend
    float ro[4], go[4], bo[4];
    #pragma unroll
    for (int i = 0; i < 4; i++) {
        float fb = fba[i];
        float r00, g00, b00, r01, g01, b01, r10, g10, b10, r11, g11, b11;
        decode_lerp3(c0[i].x, c0[i].y, c0[i].z, fb, r00, g00, b00);
        decode_lerp3(c0[i].w, c1[i].x, c1[i].y, fb, r01, g01, b01);
        decode_lerp3(c1[i].z, c1[i].w, c2[i].x, fb, r10, g10, b10);
        decode_lerp3(c2[i].y, c2[i].z, c2[i].w, fb, r11, g11, b11);
        float fr = fra[i], fg = fga[i];
        float w00 = (1.f - fr) * (1.f - fg), w01 = (1.f - fr) * fg;
        float w10 = fr * (1.f - fg),         w11 = fr * fg;
        float rx = r00 * w00 + r01 * w01 + r10 * w10 + r11 * w11;
        float ry = g00 * w00 + g01 * w01 + g10 * w10 + g11 * w11;
        float rz = b00 * w00 + b01 * w01 + b10 * w10 + b11 * w11;
        ro[i] = fminf(fmaxf(rx, 0.f), 1.f);
        go[i] = fminf(fmaxf(ry, 0.f), 1.f);
        bo[i] = fminf(fmaxf(rz, 0.f), 1.f);
    }
    float* op = out + (size_t)bimg * 3 * HW_IMG + p0;
    float4 o0 = {ro[0], ro[1], ro[2], ro[3]};
    float4 o1 = {go[0], go[1], go[2], go[3]};
    float4 o2 = {bo[0], bo[1], bo[2], bo[3]};
    *(float4*)(op) = o0;
    *(float4*)(op + HW_IMG) = o1;
    *(float4*)(op + 2 * HW_IMG) = o2;
}

extern "C" void kernel_launch(void* const* d_in, const int* in_sizes, int n_in,
                              void* d_out, int out_size, void* d_ws, size_t ws_size,
                              hipStream_t stream) {
    const float* lq  = (const float*)d_in[0];
    const float* w1  = (const float*)d_in[1];
    const float* b1  = (const float*)d_in[2];
    const float* g1  = (const float*)d_in[3];
    const float* be1 = (const float*)d_in[4];
    const float* w2  = (const float*)d_in[5];
    const float* b2  = (const float*)d_in[6];
    const float* g2  = (const float*)d_in[7];
    const float* be2 = (const float*)d_in[8];
    const float* w3  = (const float*)d_in[9];
    const float* b3  = (const float*)d_in[10];
    const float* g3  = (const float*)d_in[11];
    const float* be3 = (const float*)d_in[12];
    const float* w4  = (const float*)d_in[13];
    const float* b4  = (const float*)d_in[14];
    const float* g4  = (const float*)d_in[15];
    const float* be4 = (const float*)d_in[16];
    const float* w5  = (const float*)d_in[17];
    const float* b5  = (const float*)d_in[18];
    const float* lw  = (const float*)d_in[19];
    const float* lb  = (const float*)d_in[20];
    const float* bw  = (const float*)d_in[21];
    const float* aw  = (const float*)d_in[22];
    const float* ab  = (const float*)d_in[23];

    float* ws     = (float*)d_ws;
    float* r256   = ws;                    // 786432
    float* f1     = r256 + 786432;         // 1048576 (dead after S2; psplit4/5 aliased here)
    float* f2     = f1 + 1048576;          // 524288
    float* f3     = f2 + 524288;           // 262144
    float* f4     = f3 + 262144;           // 131072
    float* f5     = f4 + 131072;           // 32768 (4x128x8x8)
    float* codes  = f5 + 32768;            // 2048
    float* wt     = codes + 2048;          // 12
    float* vert   = wt + 12;               // 396
    float* part1  = vert + 396;            // 64 planes * 256 tiles * 2  = 32768
    float* part2  = part1 + 32768;         // 128 * 64 * 2 = 16384
    float* part3  = part2 + 16384;         // 256 * 16 * 2 = 8192
    float* spart4 = part3 + 8192;          // 512 * 4 * 2  = 4096
    float* norm1  = spart4 + 4096;         // 4*16*2  = 128
    float* norm2  = norm1 + 128;           // 4*32*2  = 256
    float* norm3  = norm2 + 256;           // 4*64*2  = 512
    float* norm4  = norm3 + 512;           // 4*128*2 = 1024
    float* stab   = norm4 + 1024;          // 12*256 BYTES = 3072 B = 768 floats (uint8 table)
    float* luts4  = stab + 768;            // 4*35937 float4 entries; 16B aligned
    float* psplit4 = f1;                   // 2*131072 = 262144 (alias, f1 dead by S4)
    float* psplit5 = f1 + 262144;          // 4*32768  = 131072
    float* cells  = ws;                    // 4*32768 cells * 16 floats = 2097152
                                           // aliases r256/f1/f2 — all dead before k_cellgen

    float* outs  = (float*)d_out;
    float* out_w = outs + (size_t)BATCH * 3 * HW_IMG;  // 12582912
    float* out_v = out_w + 12;

    k_resize<<<3072, 256, 0, stream>>>(lq, r256);
    // S1: [4,3,256,256] -> f1 [4,16,128,128]; grid 4*16*16*1*1 = 1024
    k_conv_t<3, 16, 128, 128, 1, false, true><<<1024, 256, 0, stream>>>(
        r256, nullptr, w1, b1, f1, part1);
    k_norm<256><<<64, 64, 0, stream>>>(part1, g1, be1, 1.f / 16384.f, 16, norm1);
    // S2: -> f2 [4,32,64,64]; grid 4*8*8*1*2 = 512
    k_conv_t<16, 32, 64, 64, 1, true, true><<<512, 256, 0, stream>>>(
        f1, norm1, w2, b2, f2, part2);
    k_norm<64><<<128, 64, 0, stream>>>(part2, g2, be2, 1.f / 4096.f, 32, norm2);
    // S3: -> f3 [4,64,32,32]; grid 4*4*4*1*4 = 256
    k_conv_t<32, 64, 32, 32, 1, true, true><<<256, 256, 0, stream>>>(
        f2, norm2, w3, b3, f3, part3);
    k_norm<16><<<256, 64, 0, stream>>>(part3, g3, be3, 1.f / 1024.f, 64, norm3);
    // S4: -> psplit4; grid 4*2*2*2*8 = 256; combine -> f4 [4,128,16,16] + stats
    k_conv_t<64, 128, 16, 16, 2, true, false><<<256, 256, 0, stream>>>(
        f3, norm3, w4, b4, nullptr, psplit4);
    k_combine<2, 128, 256, true><<<512, 256, 0, stream>>>(psplit4, b4, f4, spart4);
    k_norm<4><<<512, 64, 0, stream>>>(spart4, g4, be4, 1.f / 256.f, 128, norm4);
    // S5: -> psplit5; grid 4*1*1*4*8 = 128; combine -> f5 [4,128,8,8] (no IN)
    k_conv_t<128, 128, 8, 8, 4, true, false><<<128, 256, 0, stream>>>(
        f4, norm4, w5, b5, nullptr, psplit5);
    k_combine<4, 128, 64, false><<<128, 256, 0, stream>>>(psplit5, b5, f5, nullptr);
    k_pool<<<8, 256, 0, stream>>>(f5, codes);
    k_head<<<13, 64, 0, stream>>>(codes, lw, lb, aw, ab, wt, vert, stab, out_w, out_v);
    k_lutgen<<<(BATCH * LUT_D3 + 255) / 256, 256, 0, stream>>>(bw, wt, (float4*)luts4);
    k_cellgen<<<512, 256, 0, stream>>>((const float4*)luts4, (float4*)cells);
    k_transform<<<BATCH * 1024, 256, 0, stream>>>(
        lq, (const float4*)cells, vert, (const unsigned char*)stab, outs);
}

// Round 4
// 284.271 us; speedup vs baseline: 1.0907x; 1.0265x over previous
//
#include <hip/hip_runtime.h>
#include <hip/hip_fp16.h>
#include <math.h>

#define LUT_D 33
#define LUT_D3 35937   // 33^3
#define NEG 0.2f
#define BATCH 4
#define HW_IMG 1048576 // 1024*1024

// ---------------- resize 1024 -> 256 (half-pixel bilinear, scale 4 => frac=0.5) -------------
// 4 outputs per thread, float4 loads (2 rows x 16 aligned floats) + float4 store.
__global__ void k_resize(const float* __restrict__ lq, float* __restrict__ out) {
    int gid = blockIdx.x * 256 + threadIdx.x;     // over 4*3*256*64 = 196608
    if (gid >= BATCH * 3 * 256 * 64) return;
    int xq = gid & 63;
    int y  = (gid >> 6) & 255;
    int pc = gid >> 14;                            // b*3 + c
    const float* ra = lq + (size_t)pc * HW_IMG + (size_t)(4 * y + 1) * 1024 + xq * 16;
    const float4* pa = (const float4*)ra;
    const float4* pb = (const float4*)(ra + 1024);
    float4 a0 = pa[0], a1 = pa[1], a2 = pa[2], a3 = pa[3];
    float4 b0 = pb[0], b1 = pb[1], b2 = pb[2], b3 = pb[3];
    float4 o;
    o.x = 0.25f * (a0.y + a0.z + b0.y + b0.z);
    o.y = 0.25f * (a1.y + a1.z + b1.y + b1.z);
    o.z = 0.25f * (a2.y + a2.z + b2.y + b2.z);
    o.w = 0.25f * (a3.y + a3.z + b3.y + b3.z);
    ((float4*)out)[gid] = o;
}

// ---------------- tiled conv3x3 s2 p1 (+LeakyReLU if NSPLIT==1), fused input-norm -----------
template<int IC, int OC, int OH, int OW, int NSPLIT, bool NORM_IN, bool STATS_OUT>
__global__ void __launch_bounds__(256) k_conv_t(
    const float* __restrict__ in, const float* __restrict__ nrm_in,
    const float* __restrict__ w, const float* __restrict__ bias,
    float* __restrict__ out, float* __restrict__ part) {
    constexpr int IH = OH * 2, IW = OW * 2;
    constexpr int ICB = IC / NSPLIT;              // <= 32
    constexpr int TROW = 20, TSZ = 17 * TROW;     // 340 floats per ic tile
    constexpr int WQ = ICB * 9 / 4;               // float4s per oc slice
    constexpr int NTX = OW / 8, NTY = OH / 8, NOCG = OC / 16;
    constexpr int NT = NTX * NTY;
    constexpr int PX = OH * OW;

    __shared__ float sIn[ICB * TSZ];
    __shared__ float swl[16 * ICB * 9];
    __shared__ float sNm[NORM_IN ? ICB * 2 : 1];

    int id = blockIdx.x;
    int ocg   = id % NOCG;   id /= NOCG;
    int icc_i = id % NSPLIT; id /= NSPLIT;
    int tx    = id % NTX;    id /= NTX;
    int ty    = id % NTY;    id /= NTY;
    int b     = id;
    int icc   = icc_i * ICB;

    int t    = threadIdx.x;
    int lane = t >> 6;          // 0..3
    int px   = t & 63;
    int py   = px >> 3, pxx = px & 7;
    int oc0  = ocg * 16 + lane * 4;

    // ---- stage weights (vectorized) + norm pairs ----
    if (IC == ICB) {
        const float4* wsrc = (const float4*)(w + (size_t)ocg * 16 * IC * 9);
        for (int i = t; i < 16 * IC * 9 / 4; i += 256) ((float4*)swl)[i] = wsrc[i];
    } else {
        for (int i = t; i < 16 * WQ; i += 256) {
            int ol = i / WQ, qi = i % WQ;
            ((float4*)swl)[ol * WQ + qi] =
                *(const float4*)(w + ((size_t)(ocg * 16 + ol) * IC + icc) * 9 + qi * 4);
        }
    }
    if (NORM_IN) {
        for (int i = t; i < ICB * 2; i += 256) sNm[i] = nrm_in[(b * IC + icc) * 2 + i];
    }
    __syncthreads();

    // ---- stage input tile: 4 float4 + 1 halo scalar per (ic,row) ----
    int iy0 = ty * 16 - 1;
    int xbase = tx * 16;
    const float* inb = in + (size_t)(b * IC + icc) * (IH * IW);
    for (int q = t; q < ICB * 17 * 4; q += 256) {
        int ic_l = q / 68;
        int r    = q % 68;
        int row  = r >> 2, quad = r & 3;
        int iy = iy0 + row;
        float4 v = {0.f, 0.f, 0.f, 0.f};
        if (iy >= 0 && iy < IH) {
            v = *(const float4*)(inb + (size_t)ic_l * (IH * IW) + (size_t)iy * IW + xbase + quad * 4);
            if (NORM_IN) {
                float sc = sNm[ic_l * 2], sh = sNm[ic_l * 2 + 1];
                v.x = v.x * sc + sh; v.y = v.y * sc + sh;
                v.z = v.z * sc + sh; v.w = v.w * sc + sh;
            }
        }
        *(float4*)(sIn + ic_l * TSZ + row * TROW + 4 + quad * 4) = v;
    }
    for (int h = t; h < ICB * 17; h += 256) {
        int ic_l = h / 17, row = h % 17;
        int iy = iy0 + row, ix = xbase - 1;
        float v = 0.f;
        if (iy >= 0 && iy < IH && ix >= 0) {
            v = inb[(size_t)ic_l * (IH * IW) + (size_t)iy * IW + ix];
            if (NORM_IN) v = v * sNm[ic_l * 2] + sNm[ic_l * 2 + 1];
        }
        sIn[ic_l * TSZ + row * TROW + 3] = v;
    }
    __syncthreads();

    // ---- compute ----
    float acc[4];
    #pragma unroll
    for (int j = 0; j < 4; j++) acc[j] = (NSPLIT == 1) ? bias[oc0 + j] : 0.f;

    for (int i2 = 0; i2 < ICB; i2++) {
        const float* tp = sIn + i2 * TSZ + py * 2 * TROW + pxx * 2 + 3;
        float x0 = tp[0],        x1 = tp[1],        x2 = tp[2];
        float x3 = tp[TROW],     x4 = tp[TROW + 1], x5 = tp[TROW + 2];
        float x6 = tp[2 * TROW], x7 = tp[2 * TROW + 1], x8 = tp[2 * TROW + 2];
        #pragma unroll
        for (int j = 0; j < 4; j++) {
            const float* wp = swl + ((lane * 4 + j) * ICB + i2) * 9;
            acc[j] = fmaf(x0, wp[0], acc[j]);
            acc[j] = fmaf(x1, wp[1], acc[j]);
            acc[j] = fmaf(x2, wp[2], acc[j]);
            acc[j] = fmaf(x3, wp[3], acc[j]);
            acc[j] = fmaf(x4, wp[4], acc[j]);
            acc[j] = fmaf(x5, wp[5], acc[j]);
            acc[j] = fmaf(x6, wp[6], acc[j]);
            acc[j] = fmaf(x7, wp[7], acc[j]);
            acc[j] = fmaf(x8, wp[8], acc[j]);
        }
    }

    int oy = ty * 8 + py, ox = tx * 8 + pxx;
    if (NSPLIT == 1) {
        int tile = ty * NTX + tx;
        #pragma unroll
        for (int j = 0; j < 4; j++) {
            float a = acc[j];
            a = a >= 0.f ? a : NEG * a;
            out[((size_t)(b * OC + oc0 + j) * OH + oy) * OW + ox] = a;
            if (STATS_OUT) {
                float s1 = a, s2 = a * a;
                for (int off = 32; off > 0; off >>= 1) {
                    s1 += __shfl_down(s1, off, 64);
                    s2 += __shfl_down(s2, off, 64);
                }
                if (px == 0) {
                    size_t pi = ((size_t)(b * OC + oc0 + j) * NT + tile) * 2;
                    part[pi] = s1; part[pi + 1] = s2;
                }
            }
        }
    } else {
        #pragma unroll
        for (int j = 0; j < 4; j++) {
            part[(size_t)icc_i * (BATCH * OC * PX) +
                 (size_t)(b * OC + oc0 + j) * PX + oy * OW + ox] = acc[j];
        }
    }
}

// ---------------- combine ic-split partials: + bias, LeakyReLU, optional stats -------------
template<int NSPLIT, int OC, int PX, bool STATS>
__global__ void k_combine(const float* __restrict__ ps, const float* __restrict__ bias,
                          float* __restrict__ out, float* __restrict__ spart) {
    constexpr int TOT = BATCH * OC * PX;
    int e = blockIdx.x * 256 + threadIdx.x;
    if (e >= TOT) return;
    float s = 0.f;
    #pragma unroll
    for (int k = 0; k < NSPLIT; k++) s += ps[(size_t)k * TOT + e];
    int oc = (e / PX) % OC;
    s += bias[oc];
    s = s >= 0.f ? s : NEG * s;
    out[e] = s;
    if (STATS) {
        float s1 = s, s2 = s * s;
        for (int off = 32; off > 0; off >>= 1) {
            s1 += __shfl_down(s1, off, 64);
            s2 += __shfl_down(s2, off, 64);
        }
        if ((threadIdx.x & 63) == 0) {
            int widx = e >> 6;
            spart[widx * 2] = s1; spart[widx * 2 + 1] = s2;
        }
    }
}

// ---------------- reduce partial (s1,s2) -> per-(b,c) norm pair (scale, shift) -------------
template<int NT>
__global__ void k_norm(const float* __restrict__ part, const float* __restrict__ g,
                       const float* __restrict__ be, float invN, int C,
                       float* __restrict__ nrm) {
    int bc = blockIdx.x;
    int t  = threadIdx.x;  // 64
    float s1 = 0.f, s2 = 0.f;
    for (int i = t; i < NT; i += 64) {
        s1 += part[((size_t)bc * NT + i) * 2];
        s2 += part[((size_t)bc * NT + i) * 2 + 1];
    }
    #pragma unroll
    for (int off = 32; off > 0; off >>= 1) {
        s1 += __shfl_down(s1, off, 64);
        s2 += __shfl_down(s2, off, 64);
    }
    if (t == 0) {
        int c = bc % C;
        float m   = s1 * invN;
        float var = s2 * invN - m * m;
        float sc  = g[c] * rsqrtf(var + 1e-5f);
        nrm[bc * 2]     = sc;
        nrm[bc * 2 + 1] = be[c] - m * sc;
    }
}

// ---------------- AdaptiveAvgPool2d(2) on [4,128,8,8] -> codes [4,512] ---------------------
__global__ void k_pool(const float* __restrict__ f5, float* __restrict__ codes) {
    int c = blockIdx.x * 256 + threadIdx.x;   // 2048
    if (c >= 2048) return;
    int b = c >> 9;
    int rest = c & 511;
    int oc = rest >> 2, q = rest & 3;
    int py = (q >> 1) * 4, px = (q & 1) * 4;
    const float* p = f5 + ((size_t)(b * 128 + oc)) * 64;
    float s = 0.f;
    #pragma unroll
    for (int dy = 0; dy < 4; dy++)
        #pragma unroll
        for (int dx = 0; dx < 4; dx++)
            s += p[(py + dy) * 8 + px + dx];
    codes[c] = s * (1.f / 16.f);
}

// ---------------- heads + two-piece linear search table ------------------------------------
// For each (b,ch) and 256 bins u: x in [u/256,(u+1)/256) (u exact: *2^8 is lossless).
//   n0 = count(v <= u/256); vsplit = first vertex strictly inside the bin (2.0 if none).
//   piece0 (x < vsplit): idx = clamp(n0,1,32);   piece1 (x >= vsplit): idx = clamp(n0+1,1,32).
//   coord = m*x + c with m = 1/(v[idx]-v[idx-1]+1e-8), c = (idx-1) - v[idx-1]*m.
// Exact when <=1 interior vertex; >=2 interior (softmax intervals ~1/32 >> 1/256, so ~never)
// sets m0 = NaN -> k_transform falls back to exact binary search. Entry: A4=(vs,m0,c0,m1), C1.
__global__ void k_head(const float* __restrict__ codes, const float* __restrict__ lw,
                       const float* __restrict__ lb, const float* __restrict__ aw,
                       const float* __restrict__ ab, float* __restrict__ wt,
                       float* __restrict__ vert, float* __restrict__ tabA,
                       float* __restrict__ tabC, float* __restrict__ out_w,
                       float* __restrict__ out_v) {
    int blk = blockIdx.x;
    int t = threadIdx.x;  // 64 threads
    if (blk == 12) {
        if (t < 48) {
            int j = t >> 2, q = t & 3;          // 12 outputs x 4 threads
            int b = j / 3, jj = j % 3;
            const float4* c4 = (const float4*)(codes + b * 512 + q * 128);
            const float4* l4 = (const float4*)(lw + jj * 512 + q * 128);
            float s = 0.f;
            for (int k = 0; k < 32; k++) {
                float4 cv = c4[k], lv = l4[k];
                s += cv.x * lv.x + cv.y * lv.y + cv.z * lv.z + cv.w * lv.w;
            }
            s += __shfl_down(s, 2, 64);
            s += __shfl_down(s, 1, 64);
            if (q == 0) {
                s += lb[jj];
                wt[j] = s;
                out_w[j] = s;
            }
        }
        return;
    }
    int b = blk / 3, ch = blk % 3;
    __shared__ float y[32];
    __shared__ float vsh[33];
    {   // logits: 32 outputs x 2 threads (k-halves), float4 loads
        int m = t & 31, half = t >> 5;
        const float4* c4 = (const float4*)(codes + b * 512 + half * 256);
        const float4* a4 = (const float4*)(aw + (size_t)(ch * 32 + m) * 512 + half * 256);
        float s = (half == 0) ? ab[ch * 32 + m] : 0.f;
        for (int k = 0; k < 64; k++) {
            float4 cv = c4[k], av = a4[k];
            s += cv.x * av.x + cv.y * av.y + cv.z * av.z + cv.w * av.w;
        }
        s += __shfl_down(s, 32, 64);
        if (half == 0) y[m] = s;
    }
    __syncthreads();
    if (t == 0) {
        float mx = y[0];
        for (int m = 1; m < 32; m++) mx = fmaxf(mx, y[m]);
        float e[32];
        float sum = 0.f;
        for (int m = 0; m < 32; m++) { e[m] = expf(y[m] - mx); sum += e[m]; }
        float inv = 1.f / sum;
        float cum = 0.f;
        float* vb = vert + (b * 3 + ch) * 33;
        float* ob = out_v + (b * 3 + ch) * 33;
        vb[0] = 0.f; ob[0] = 0.f; vsh[0] = 0.f;
        for (int m = 0; m < 32; m++) {
            cum += e[m] * inv;
            vb[m + 1] = cum; ob[m + 1] = cum; vsh[m + 1] = cum;
        }
    }
    __syncthreads();
    float4* A4 = ((float4*)tabA) + (b * 3 + ch) * 256;
    float*  C1 = tabC + (b * 3 + ch) * 256;
    for (int u = t; u < 256; u += 64) {
        float lo = (float)u * (1.f / 256.f);        // exact
        float hi = (float)(u + 1) * (1.f / 256.f);  // exact
        int n0 = 0, nin = 0;
        float vs = 2.0f;
        #pragma unroll
        for (int m = 0; m < 33; m++) {
            float vm = vsh[m];
            n0 += (vm <= lo) ? 1 : 0;
            if (vm > lo && vm < hi) { if (nin == 0) vs = vm; nin++; }
        }
        int i0 = n0 < 1 ? 1 : (n0 > 32 ? 32 : n0);
        int i1 = (n0 + 1) < 1 ? 1 : ((n0 + 1) > 32 ? 32 : (n0 + 1));
        float m0 = 1.f / (vsh[i0] - vsh[i0 - 1] + 1e-8f);
        float c0 = (float)(i0 - 1) - vsh[i0 - 1] * m0;
        float m1 = 1.f / (vsh[i1] - vsh[i1 - 1] + 1e-8f);
        float c1 = (float)(i1 - 1) - vsh[i1 - 1] * m1;
        if (nin >= 2) { vs = 2.0f; m0 = __int_as_float(0x7fc00000); c0 = 0.f; }
        A4[u] = make_float4(vs, m0, c0, m1);
        C1[u] = c1;
    }
}

// ---------------- LUT generation: fp16 blue-pair entries ------------------------------------
__global__ void k_lutgen(const float* __restrict__ bw, const float* __restrict__ wt,
                         float4* __restrict__ lutp) {
    int gid = blockIdx.x * 256 + threadIdx.x;     // over 4*35937
    if (gid >= BATCH * LUT_D3) return;
    int b = gid / LUT_D3;
    int cell = gid - b * LUT_D3;
    int k = cell % LUT_D;
    int cn = (k < LUT_D - 1) ? cell + 1 : cell;
    float w0 = wt[b * 3], w1 = wt[b * 3 + 1], w2 = wt[b * 3 + 2];
    const float* r0p = bw + (size_t)(0 * LUT_D3 + cell) * 3;
    const float* g0p = bw + (size_t)(1 * LUT_D3 + cell) * 3;
    const float* b0p = bw + (size_t)(2 * LUT_D3 + cell) * 3;
    const float* r1p = bw + (size_t)(0 * LUT_D3 + cn) * 3;
    const float* g1p = bw + (size_t)(1 * LUT_D3 + cn) * 3;
    const float* b1p = bw + (size_t)(2 * LUT_D3 + cn) * 3;
    union { float4 f4; __half h[8]; } u;
    u.h[0] = __float2half_rn(r0p[0] * w0 + r0p[1] * w1 + r0p[2] * w2);
    u.h[1] = __float2half_rn(g0p[0] * w0 + g0p[1] * w1 + g0p[2] * w2);
    u.h[2] = __float2half_rn(b0p[0] * w0 + b0p[1] * w1 + b0p[2] * w2);
    u.h[3] = __float2half_rn(r1p[0] * w0 + r1p[1] * w1 + r1p[2] * w2);
    u.h[4] = __float2half_rn(g1p[0] * w0 + g1p[1] * w1 + g1p[2] * w2);
    u.h[5] = __float2half_rn(b1p[0] * w0 + b1p[1] * w1 + b1p[2] * w2);
    u.h[6] = __float2half_rn(0.f);
    u.h[7] = __float2half_rn(0.f);
    lutp[gid] = u.f4;
}

// ---------------- cell-gather table: one 48B record per (i0,j0,k0) cell, 64B stride --------
__global__ void k_cellgen(const float4* __restrict__ lutp, float4* __restrict__ cells) {
    int gid = blockIdx.x * 256 + threadIdx.x;     // 4*32768 = 131072
    if (gid >= BATCH * 32768) return;
    int b = gid >> 15;
    int cell = gid & 32767;
    int k0 = cell & 31, j0 = (cell >> 5) & 31, i0 = cell >> 10;
    const float4* L = lutp + (size_t)b * LUT_D3;
    int base = (i0 * LUT_D + j0) * LUT_D + k0;
    float4 e00 = L[base];
    float4 e01 = L[base + LUT_D];
    float4 e10 = L[base + LUT_D * LUT_D];
    float4 e11 = L[base + LUT_D * LUT_D + LUT_D];
    float4 o0, o1, o2;
    o0.x = e00.x; o0.y = e00.y; o0.z = e00.z;   // c00 words 0..2
    o0.w = e01.x; o1.x = e01.y; o1.y = e01.z;   // c01 words 0..2
    o1.z = e10.x; o1.w = e10.y; o2.x = e10.z;   // c10 words 0..2
    o2.y = e11.x; o2.z = e11.y; o2.w = e11.z;   // c11 words 0..2
    float4* dst = cells + (size_t)gid * 4;      // 4th slot never written/read
    dst[0] = o0; dst[1] = o1; dst[2] = o2;
}

// ---------------- per-pixel linear-table search + trilinear LUT sample ---------------------
__device__ __forceinline__ void searchL(const float4* __restrict__ A,
                                        const float* __restrict__ C,
                                        const float* __restrict__ v33,
                                        float x, int& i0, float& f) {
    int u = (int)(x * 256.f);                   // exact floor (x*2^8 lossless)
    u = u < 0 ? 0 : (u > 255 ? 255 : u);
    float4 e = A[u];                            // vs, m0, c0, m1
    float c1 = C[u];
    float coord = (x < e.x) ? fmaf(e.y, x, e.z) : fmaf(e.w, x, c1);
    if (!(coord == coord)) {                    // NaN marker: exact fallback (~never)
        int lo = 0, hi = LUT_D;
        while (lo < hi) { int mid = (lo + hi) >> 1; if (v33[mid] <= x) lo = mid + 1; else hi = mid; }
        int idx = lo < 1 ? 1 : (lo > LUT_D - 1 ? LUT_D - 1 : lo);
        float vl = v33[idx - 1], vh = v33[idx];
        coord = (float)(idx - 1) + (x - vl) / (vh - vl + 1e-8f);
    }
    coord = fminf(fmaxf(coord, 0.f), (float)(LUT_D - 1));
    i0 = (int)coord;
    if (i0 > LUT_D - 2) i0 = LUT_D - 2;
    f = coord - (float)i0;
}

// decode one corner (3 packed fp16 words = r0,g0,b0,r1,g1,b1), lerp along blue
__device__ __forceinline__ void decode_lerp3(float wa, float wb, float wc, float fb,
                                             float& rv, float& gv, float& bv) {
    union { float f; __half2 h; } u0, u1, u2;
    u0.f = wa; u1.f = wb; u2.f = wc;
    float2 a = __half22float2(u0.h);   // r0, g0
    float2 b = __half22float2(u1.h);   // b0, r1
    float2 c = __half22float2(u2.h);   // g1, b1
    rv = fmaf(fb, b.y - a.x, a.x);
    gv = fmaf(fb, c.x - a.y, a.y);
    bv = fmaf(fb, c.y - b.x, b.x);
}

__global__ void __launch_bounds__(256) k_transform(const float* __restrict__ lq,
                                                   const float4* __restrict__ cells,
                                                   const float* __restrict__ vert,
                                                   const float* __restrict__ gA,
                                                   const float* __restrict__ gC,
                                                   float* __restrict__ out) {
    int bimg = blockIdx.x >> 10;                  // 1024 blocks per image
    int blk  = blockIdx.x & 1023;
    __shared__ float4 sA[3 * 256];
    __shared__ float  sC[3 * 256];
    __shared__ float  sv[3 * LUT_D + 1];

    // issue pixel loads before the staging barrier (independent of LDS)
    int p0 = blk * 1024 + threadIdx.x * 4;        // 4 px per thread
    const float* lr = lq + (size_t)bimg * 3 * HW_IMG + p0;
    float4 r4 = *(const float4*)(lr);
    float4 g4 = *(const float4*)(lr + HW_IMG);
    float4 b4 = *(const float4*)(lr + 2 * HW_IMG);

    const float4* gA4 = (const float4*)gA;
    for (int i = threadIdx.x; i < 768; i += 256) sA[i] = gA4[bimg * 768 + i];
    for (int i = threadIdx.x; i < 192; i += 256)
        ((float4*)sC)[i] = ((const float4*)gC)[bimg * 192 + i];
    if (threadIdx.x < 99) sv[threadIdx.x] = vert[bimg * 99 + threadIdx.x];
    __syncthreads();

    float rr[4] = {r4.x, r4.y, r4.z, r4.w};
    float gg[4] = {g4.x, g4.y, g4.z, g4.w};
    float bb[4] = {b4.x, b4.y, b4.z, b4.w};

    // phase 1: all searches (flat, loop-free)
    int cidx[4];
    float fra[4], fga[4], fba[4];
    #pragma unroll
    for (int i = 0; i < 4; i++) {
        int i0, j0, k0;
        searchL(sA,       sC,       sv,      rr[i], i0, fra[i]);
        searchL(sA + 256, sC + 256, sv + 33, gg[i], j0, fga[i]);
        searchL(sA + 512, sC + 512, sv + 66, bb[i], k0, fba[i]);
        cidx[i] = ((i0 * 32 + j0) << 5) + k0;
    }
    // phase 2: issue all cell loads (4 independent lines -> max MLP)
    float4 c0[4], c1[4], c2[4];
    #pragma unroll
    for (int i = 0; i < 4; i++) {
        const float4* p = cells + (((size_t)(bimg << 15) + cidx[i]) << 2);
        c0[i] = p[0]; c1[i] = p[1]; c2[i] = p[2];
    }
    // phase 3: decode + bilinear blend
    float ro[4], go[4], bo[4];
    #pragma unroll
    for (int i = 0; i < 4; i++) {
        float fb = fba[i];
        float r00, g00, b00, r01, g01, b01, r10, g10, b10, r11, g11, b11;
        decode_lerp3(c0[i].x, c0[i].y, c0[i].z, fb, r00, g00, b00);
        decode_lerp3(c0[i].w, c1[i].x, c1[i].y, fb, r01, g01, b01);
        decode_lerp3(c1[i].z, c1[i].w, c2[i].x, fb, r10, g10, b10);
        decode_lerp3(c2[i].y, c2[i].z, c2[i].w, fb, r11, g11, b11);
        float fr = fra[i], fg = fga[i];
        float w00 = (1.f - fr) * (1.f - fg), w01 = (1.f - fr) * fg;
        float w10 = fr * (1.f - fg),         w11 = fr * fg;
        float rx = r00 * w00 + r01 * w01 + r10 * w10 + r11 * w11;
        float ry = g00 * w00 + g01 * w01 + g10 * w10 + g11 * w11;
        float rz = b00 * w00 + b01 * w01 + b10 * w10 + b11 * w11;
        ro[i] = fminf(fmaxf(rx, 0.f), 1.f);
        go[i] = fminf(fmaxf(ry, 0.f), 1.f);
        bo[i] = fminf(fmaxf(rz, 0.f), 1.f);
    }
    float* op = out + (size_t)bimg * 3 * HW_IMG + p0;
    float4 o0 = {ro[0], ro[1], ro[2], ro[3]};
    float4 o1 = {go[0], go[1], go[2], go[3]};
    float4 o2 = {bo[0], bo[1], bo[2], bo[3]};
    *(float4*)(op) = o0;
    *(float4*)(op + HW_IMG) = o1;
    *(float4*)(op + 2 * HW_IMG) = o2;
}

extern "C" void kernel_launch(void* const* d_in, const int* in_sizes, int n_in,
                              void* d_out, int out_size, void* d_ws, size_t ws_size,
                              hipStream_t stream) {
    const float* lq  = (const float*)d_in[0];
    const float* w1  = (const float*)d_in[1];
    const float* b1  = (const float*)d_in[2];
    const float* g1  = (const float*)d_in[3];
    const float* be1 = (const float*)d_in[4];
    const float* w2  = (const float*)d_in[5];
    const float* b2  = (const float*)d_in[6];
    const float* g2  = (const float*)d_in[7];
    const float* be2 = (const float*)d_in[8];
    const float* w3  = (const float*)d_in[9];
    const float* b3  = (const float*)d_in[10];
    const float* g3  = (const float*)d_in[11];
    const float* be3 = (const float*)d_in[12];
    const float* w4  = (const float*)d_in[13];
    const float* b4  = (const float*)d_in[14];
    const float* g4  = (const float*)d_in[15];
    const float* be4 = (const float*)d_in[16];
    const float* w5  = (const float*)d_in[17];
    const float* b5  = (const float*)d_in[18];
    const float* lw  = (const float*)d_in[19];
    const float* lb  = (const float*)d_in[20];
    const float* bw  = (const float*)d_in[21];
    const float* aw  = (const float*)d_in[22];
    const float* ab  = (const float*)d_in[23];

    float* ws     = (float*)d_ws;
    float* r256   = ws;                    // 786432
    float* f1     = r256 + 786432;         // 1048576 (dead after S2; psplit4/5 aliased here)
    float* f2     = f1 + 1048576;          // 524288
    float* f3     = f2 + 524288;           // 262144
    float* f4     = f3 + 262144;           // 131072
    float* f5     = f4 + 131072;           // 32768 (4x128x8x8)
    float* codes  = f5 + 32768;            // 2048
    float* wt     = codes + 2048;          // 12
    float* vert   = wt + 12;               // 396
    float* part1  = vert + 396;            // 64 planes * 256 tiles * 2  = 32768
    float* part2  = part1 + 32768;         // 128 * 64 * 2 = 16384
    float* part3  = part2 + 16384;         // 256 * 16 * 2 = 8192
    float* spart4 = part3 + 8192;          // 512 * 4 * 2  = 4096
    float* norm1  = spart4 + 4096;         // 4*16*2  = 128
    float* norm2  = norm1 + 128;           // 4*32*2  = 256
    float* norm3  = norm2 + 256;           // 4*64*2  = 512
    float* norm4  = norm3 + 512;           // 4*128*2 = 1024
    float* tabA   = norm4 + 1024;          // 12 (b,ch) * 256 bins * float4 = 12288 floats
    float* tabC   = tabA + 12288;          // 12 * 256 = 3072 floats
    float* luts4  = tabC + 3072;           // 4*35937 float4 entries; 16B aligned
    float* psplit4 = f1;                   // 4*131072 = 524288 (alias, f1 dead by S4)
    float* psplit5 = f1 + 524288;          // 8*32768  = 262144
    float* cells  = ws;                    // 4*32768 cells * 16 floats = 2097152
                                           // aliases r256/f1/f2-head — all dead by k_cellgen

    float* outs  = (float*)d_out;
    float* out_w = outs + (size_t)BATCH * 3 * HW_IMG;  // 12582912
    float* out_v = out_w + 12;

    k_resize<<<768, 256, 0, stream>>>(lq, r256);
    // S1: [4,3,256,256] -> f1 [4,16,128,128]; grid 4*16*16*1*1 = 1024
    k_conv_t<3, 16, 128, 128, 1, false, true><<<1024, 256, 0, stream>>>(
        r256, nullptr, w1, b1, f1, part1);
    k_norm<256><<<64, 64, 0, stream>>>(part1, g1, be1, 1.f / 16384.f, 16, norm1);
    // S2: -> f2 [4,32,64,64]; grid 4*8*8*1*2 = 512
    k_conv_t<16, 32, 64, 64, 1, true, true><<<512, 256, 0, stream>>>(
        f1, norm1, w2, b2, f2, part2);
    k_norm<64><<<128, 64, 0, stream>>>(part2, g2, be2, 1.f / 4096.f, 32, norm2);
    // S3: -> f3 [4,64,32,32]; grid 4*4*4*1*4 = 256
    k_conv_t<32, 64, 32, 32, 1, true, true><<<256, 256, 0, stream>>>(
        f2, norm2, w3, b3, f3, part3);
    k_norm<16><<<256, 64, 0, stream>>>(part3, g3, be3, 1.f / 1024.f, 64, norm3);
    // S4: -> psplit4; grid 4*2*2*4*8 = 512; combine -> f4 [4,128,16,16] + stats
    k_conv_t<64, 128, 16, 16, 4, true, false><<<512, 256, 0, stream>>>(
        f3, norm3, w4, b4, nullptr, psplit4);
    k_combine<4, 128, 256, true><<<512, 256, 0, stream>>>(psplit4, b4, f4, spart4);
    k_norm<4><<<512, 64, 0, stream>>>(spart4, g4, be4, 1.f / 256.f, 128, norm4);
    // S5: -> psplit5; grid 4*1*1*8*8 = 256; combine -> f5 [4,128,8,8] (no IN)
    k_conv_t<128, 128, 8, 8, 8, true, false><<<256, 256, 0, stream>>>(
        f4, norm4, w5, b5, nullptr, psplit5);
    k_combine<8, 128, 64, false><<<128, 256, 0, stream>>>(psplit5, b5, f5, nullptr);
    k_pool<<<8, 256, 0, stream>>>(f5, codes);
    k_head<<<13, 64, 0, stream>>>(codes, lw, lb, aw, ab, wt, vert, tabA, tabC, out_w, out_v);
    k_lutgen<<<(BATCH * LUT_D3 + 255) / 256, 256, 0, stream>>>(bw, wt, (float4*)luts4);
    k_cellgen<<<512, 256, 0, stream>>>((const float4*)luts4, (float4*)cells);
    k_transform<<<BATCH * 1024, 256, 0, stream>>>(
        lq, (const float4*)cells, vert, tabA, tabC, outs);
}